// Round 6
// baseline (357.203 us; speedup 1.0000x reference)
//
#include <hip/hip_runtime.h>
#include <hip/hip_bf16.h>

// Problem: B=16, N=1024, D=768, H=12, E=64.  M = B*N = 16384.
// Pipeline: cvt_x -> pack_w -> gemm_bt<0> (QKV, writes Q,K,V^T bf16) ->
//           attn (split-wait LDS pipeline, swapped QK^T, reg softmax) ->
//           gemm_bt<1> (f32 out)

typedef __attribute__((ext_vector_type(4))) float    f32x4;
typedef __attribute__((ext_vector_type(8))) short    s16x8;
typedef __attribute__((ext_vector_type(4))) short    s16x4;
typedef __attribute__((ext_vector_type(4))) unsigned u32x4;
typedef __attribute__((ext_vector_type(2))) unsigned u32x2;

static __device__ __forceinline__ short f2bf(float f) {
  unsigned u = __builtin_bit_cast(unsigned, f);
  u += 0x7fff + ((u >> 16) & 1);          // round-to-nearest-even
  return (short)(u >> 16);
}

// v_cvt_pk_bf16_f32: D[15:0]=bf16(lo), D[31:16]=bf16(hi)
static __device__ __forceinline__ unsigned cvt_pk_bf16(float lo, float hi) {
  unsigned r;
  asm("v_cvt_pk_bf16_f32 %0, %1, %2" : "=v"(r) : "v"(lo), "v"(hi));
  return r;
}

static __device__ __forceinline__ void gload16(const void* g, void* l) {
  __builtin_amdgcn_global_load_lds(
      (const __attribute__((address_space(1))) void*)g,
      (__attribute__((address_space(3))) void*)l, 16, 0, 0);
}

// ---------------------------------------------------------------- converts --
__global__ void cvt_x_kernel(const float* __restrict__ x, short* __restrict__ xb, int n4) {
  int stride = gridDim.x * blockDim.x;
  for (int t = blockIdx.x * blockDim.x + threadIdx.x; t < n4; t += stride) {
    f32x4 v = *(const f32x4*)(x + 4 * (size_t)t);
    s16x4 o;
#pragma unroll
    for (int i = 0; i < 4; ++i) o[i] = f2bf(v[i]);
    *(s16x4*)(xb + 4 * (size_t)t) = o;
  }
}

// Pack weights bf16 into Wall[3072][768]: rows = [Q | K | V | Wo] with Q/K
// de-interleaved from Wqk's (h, e, 2) column layout.
__global__ void pack_w_kernel(const float* __restrict__ Wqk, const float* __restrict__ qkb,
                              const float* __restrict__ Wv,  const float* __restrict__ vb,
                              const float* __restrict__ Wo,  const float* __restrict__ ob,
                              short* __restrict__ Wall, float* __restrict__ ball) {
  int stride = gridDim.x * blockDim.x;
  for (int t = blockIdx.x * blockDim.x + threadIdx.x; t < 3072 * 768; t += stride) {
    int j = t / 768, k = t - j * 768;
    float v;
    if (j < 768)        v = Wqk[(((j   >> 6) << 7) + ((j    & 63) << 1) + 0) * 768 + k];
    else if (j < 1536)  { int jj = j -  768; v = Wqk[(((jj >> 6) << 7) + ((jj & 63) << 1) + 1) * 768 + k]; }
    else if (j < 2304)  { int jj = j - 1536; v = Wv[jj * 768 + k]; }
    else                { int jj = j - 2304; v = Wo[jj * 768 + k]; }
    Wall[t] = f2bf(v);
  }
  for (int t = blockIdx.x * blockDim.x + threadIdx.x; t < 3072; t += stride) {
    float v;
    if (t < 768)        v = qkb[((t >> 6) << 7) + ((t & 63) << 1)];
    else if (t < 1536)  { int jj = t -  768; v = qkb[((jj >> 6) << 7) + ((jj & 63) << 1) + 1]; }
    else if (t < 2304)  v = vb[t - 1536];
    else                v = ob[t - 2304];
    ball[t] = v;
  }
}

// ------------------------------------------------------------------- GEMM ---
// C[m][j] = sum_k A[m][k]*Bw[j][k] + bias[j].  128x128 tile, BK=32, 4 waves,
// 16x16x32 MFMA.  A: 6-deep LDS ring (48KB), stage distance 5, counted vmcnt
// ledger (12 -> 8 steady -> 6/4/0 drain).  B: NOT staged -- read per K-step
// directly from L2-resident weights into a 3-deep register pipeline (halves
// LDS port traffic; L1 serves the 2x wave duplication).  A keeps the
// 16B-granule XOR swizzle g^((r>>1)&3) both-sides (verified r4, 18x conflict
// cut).  Coalesced epilogue via per-wave padded LDS transpose tile.
// Bijective XCD swizzle; grids give exactly 3 (MODE 0) / 1 (MODE 1) rounds
// at 3 blocks/CU with zero tail.
template <int MODE>
__global__ __launch_bounds__(256, 3)
void gemm_bt(const short* __restrict__ A, const short* __restrict__ Bw,
             const float* __restrict__ bias,
             short* __restrict__ Qo, short* __restrict__ Ko, short* __restrict__ Vo,
             float* __restrict__ Fo) {
  __shared__ short Ls[6][4096];            // A ring, 6 x 8KB = 48 KB
  const int tid = threadIdx.x;
  const int lane = tid & 63, wid = tid >> 6;
  const int wr = wid >> 1, wc = wid & 1;
  const int lrow = lane & 15, lk = lane >> 4;
  int lin = blockIdx.y * gridDim.x + blockIdx.x;
  const int cpx = (gridDim.x * gridDim.y) >> 3;
  lin = (lin & 7) * cpx + (lin >> 3);
  const int n0 = (lin % gridDim.x) * 128;
  const int m0 = (lin / gridDim.x) * 128;

  // A staging: thread owns 16B granules tid, tid+256 of each 8KB tile.
  // phys slot j = tid&3 at row r = tid>>2 holds content slot j ^ ((r>>1)&3).
  const int swzc = ((tid & 3) ^ ((tid >> 3) & 3)) << 3;   // source col offset
  const short* sA = A + (size_t)(m0 + (tid >> 2)) * 768 + swzc;
  // read side: content slot lk at phys slot lk ^ ((row>>1)&3)
  const int xo = (lk ^ ((lrow >> 1) & 3)) << 3;

  // B fragments straight from global (no swizzle): row n0+wc*64+nf*16+lrow
  const short* brow = Bw + (size_t)(n0 + wc * 64 + lrow) * 768 + lk * 8;
#define BLOAD(dst, kt) do { _Pragma("unroll")                              \
    for (int nf = 0; nf < 4; ++nf)                                         \
      dst[nf] = *(const s16x8*)(brow + (size_t)nf * 16 * 768 + (kt) * 32); \
  } while (0)

  f32x4 acc[4][4] = {};
  s16x8 bA[4], bB[4], bC[4];

  // prologue: b(0),b(1) -> regs; stage A tiles 0..4 (FIFO defines vmcnt)
  BLOAD(bA, 0);
  BLOAD(bB, 1);
  asm volatile("" ::: "memory");           // pin issue order: b before A-DMA
#pragma unroll
  for (int pt = 0; pt < 5; ++pt) {
    const short* gA = sA + pt * 32;
    gload16(gA,            &Ls[pt][tid * 8]);
    gload16(gA + 64 * 768, &Ls[pt][(256 + tid) * 8]);
  }
  asm volatile("s_waitcnt vmcnt(12)" ::: "memory");   // b(0) + A(0) landed
  __builtin_amdgcn_s_barrier();

  // K-loop: 24 steps as 4 x 6 statically-indexed sub-steps.
  // Per step t: load b(t+2) -> reg ring; stage A(t+5) -> LDS ring; 16 MFMA;
  // boundary wait vmcnt(N) with N = 12(t=0), 8(t<=18), 6(19), 4(20,21), 0(22).
#define SUBSTEP(J, BUSE, BLD) do {                                          \
    const int t = t0 + (J);                                                 \
    if (t + 2 < 24) BLOAD(BLD, t + 2);                                      \
    asm volatile("" ::: "memory");                                          \
    if (t + 5 < 24) {                                                       \
      const short* gA = sA + (t + 5) * 32;                                  \
      short* d = &Ls[((J) + 5) % 6][0];                                     \
      gload16(gA,            d + tid * 8);                                  \
      gload16(gA + 64 * 768, d + (256 + tid) * 8);                          \
    }                                                                       \
    s16x8 a[4];                                                             \
    _Pragma("unroll") for (int mf = 0; mf < 4; ++mf)                        \
      a[mf] = *(const s16x8*)&Ls[J][(wr * 64 + mf * 16 + lrow) * 32 + xo];  \
    __builtin_amdgcn_s_setprio(1);                                          \
    _Pragma("unroll") for (int mf = 0; mf < 4; ++mf)                        \
      _Pragma("unroll") for (int nf = 0; nf < 4; ++nf)                      \
        acc[mf][nf] = __builtin_amdgcn_mfma_f32_16x16x32_bf16(              \
            a[mf], BUSE[nf], acc[mf][nf], 0, 0, 0);                         \
    __builtin_amdgcn_s_setprio(0);                                          \
    if (t == 0)       asm volatile("s_waitcnt vmcnt(12)" ::: "memory");     \
    else if (t <= 18) asm volatile("s_waitcnt vmcnt(8)"  ::: "memory");     \
    else if (t == 19) asm volatile("s_waitcnt vmcnt(6)"  ::: "memory");     \
    else if (t <= 21) asm volatile("s_waitcnt vmcnt(4)"  ::: "memory");     \
    else if (t == 22) asm volatile("s_waitcnt vmcnt(0)"  ::: "memory");     \
    if (t < 23) __builtin_amdgcn_s_barrier();                               \
  } while (0)

  for (int u = 0; u < 4; ++u) {
    const int t0 = u * 6;
    SUBSTEP(0, bA, bC); SUBSTEP(1, bB, bA); SUBSTEP(2, bC, bB);
    SUBSTEP(3, bA, bC); SUBSTEP(4, bB, bA); SUBSTEP(5, bC, bB);
  }
#undef SUBSTEP
#undef BLOAD

  __syncthreads();                         // repurpose Ls for epilogue
  // per-wave transpose tile [16][68] f32 = 4352 B (padded, conflict-free)
  float* tw = (float*)((char*)&Ls[0][0] + wid * 4352);
  const int creg = n0 + wc * 64;           // this wave's 64-col range
  const int g4 = lk * 4;

  if (MODE == 0 && creg >= 1536) {
    // V^T [b,h,e,n]: direct stores (4 n's contiguous -> 8B segments)
    const int h = (creg - 1536) >> 6;
#pragma unroll
    for (int nf = 0; nf < 4; ++nf) {
      const int e = nf * 16 + lrow;
      const float bs = bias[creg + e];
#pragma unroll
      for (int mf = 0; mf < 4; ++mf) {
        f32x4 v = acc[mf][nf];
        const int mb = m0 + wr * 64 + mf * 16 + g4;
        const int bi = mb >> 10, n = mb & 1023;
        s16x4 pk;
#pragma unroll
        for (int i = 0; i < 4; ++i) pk[i] = f2bf(v[i] + bs);
        *(s16x4*)(Vo + (((size_t)bi * 12 + h) * 64 + e) * 1024 + n) = pk;
      }
    }
  } else {
#pragma unroll
    for (int mf = 0; mf < 4; ++mf) {
      // scatter fragment mf (rows g4..g4+3, col nf*16+lrow) into tw, +bias
#pragma unroll
      for (int nf = 0; nf < 4; ++nf) {
        const float bs = bias[creg + nf * 16 + lrow];
#pragma unroll
        for (int i = 0; i < 4; ++i)
          tw[(g4 + i) * 68 + nf * 16 + lrow] = acc[mf][nf][i] + bs;
      }
      // wave-internal transpose readback (ds ops ordered; no barrier needed)
      if (MODE == 0) {
        const int hq = (creg >> 6) % 12;
        short* dst0 = (creg < 768) ? Qo : Ko;
#pragma unroll
        for (int p = 0; p < 2; ++p) {
          const int row = (lane >> 3) + p * 8, c8 = (lane & 7) * 8;
          f32x4 v0 = *(const f32x4*)&tw[row * 68 + c8];
          f32x4 v1 = *(const f32x4*)&tw[row * 68 + c8 + 4];
          u32x4 pk;
          pk[0] = cvt_pk_bf16(v0[0], v0[1]);
          pk[1] = cvt_pk_bf16(v0[2], v0[3]);
          pk[2] = cvt_pk_bf16(v1[0], v1[1]);
          pk[3] = cvt_pk_bf16(v1[2], v1[3]);
          const int m = m0 + wr * 64 + mf * 16 + row;
          const int bi = m >> 10, n = m & 1023;
          *(s16x8*)(dst0 + (((size_t)bi * 12 + hq) << 16) + ((size_t)n << 6) + c8) =
              __builtin_bit_cast(s16x8, pk);
        }
      } else {
#pragma unroll
        for (int p = 0; p < 4; ++p) {
          const int row = (lane >> 4) + p * 4, c4 = (lane & 15) * 4;
          f32x4 v = *(const f32x4*)&tw[row * 68 + c4];
          const int m = m0 + wr * 64 + mf * 16 + row;
          *(f32x4*)&Fo[(size_t)m * 768 + creg + c4] = v;
        }
      }
    }
  }
}

// -------------------------------------------------------------- attention ---
// grid (192 bh, 8 qt); 4 waves x 32 q-rows share one K/V tile via LDS.
// KV tile = 64. Split-wait pipeline: top-of-iter vmcnt(2) waits only for
// K(t) (V(t) still in flight); after QK^T+softmax, vmcnt(4) waits for V(t)
// while K/V(t+1) stay in flight. One barrier per tile. LDS 16B-granule XOR
// swizzle (g ^= row&7) both sides (rule #21). Swapped QK^T keeps softmax
// lane-local; P = exp(s-16) (shift cancels in normalization); P packed
// in-register feeds PV's B-operand with k-slot permutation sigma matched by
// two 8B V reads.
__global__ __launch_bounds__(256, 4)
void attn_kernel(const short* __restrict__ Q, const short* __restrict__ K,
                 const short* __restrict__ VT, short* __restrict__ Co) {
  __shared__ short Ks[2][4096];
  __shared__ short Vs[2][4096];
  const int tid = threadIdx.x, lane = tid & 63, wid = tid >> 6;
  const int lrow = lane & 15, lk = lane >> 4;
  const int bh = blockIdx.x, qt = blockIdx.y;
  const int bi = bh / 12, h = bh - bi * 12;
  const int q0 = qt * 128 + wid * 32;
  const size_t base = (size_t)bh << 16;   // * N*E = 65536

  const short* Kb = K  + base;
  const short* Vb = VT + base;

  const int sr = tid >> 3, sj = tid & 7;
  const int jsw = (sj ^ (sr & 7)) << 3;            // element offset in row
  const short* ksrc0 = Kb + (size_t)sr * 64 + jsw;
  const short* vsrc0 = Vb + (size_t)sr * 1024 + jsw;

  const int rs = lrow & 7;
  const int ko0 = (lk ^ rs) << 3;
  const int ko1 = ((4 | lk) ^ rs) << 3;
  const int vhalf = (lk & 1) * 4;
  int vo[2][2];
#pragma unroll
  for (int kh = 0; kh < 2; ++kh) {
    const int g = kh * 4 + (lk >> 1);
    vo[kh][0] = ((g ^ rs) << 3) + vhalf;
    vo[kh][1] = (((g | 2) ^ rs) << 3) + vhalf;
  }

  s16x8 qf[2][2];
#pragma unroll
  for (int qi = 0; qi < 2; ++qi)
#pragma unroll
    for (int kk = 0; kk < 2; ++kk)
      qf[qi][kk] = *(const s16x8*)&Q[base + (size_t)(q0 + qi * 16 + lrow) * 64 + kk * 32 + lk * 8];

  f32x4 o[2][4] = {};
  float lr[2] = {0.f, 0.f};

  // prologue: K(0) then V(0)  (order defines vmcnt ledger)
  gload16(ksrc0,             &Ks[0][tid * 8]);
  gload16(ksrc0 + 32 * 64,   &Ks[0][(tid + 256) * 8]);
  gload16(vsrc0,             &Vs[0][tid * 8]);
  gload16(vsrc0 + 32 * 1024, &Vs[0][(tid + 256) * 8]);

  for (int t = 0; t < 16; ++t) {
    const int cur = t & 1;
    asm volatile("s_waitcnt vmcnt(2)" ::: "memory");   // K(t) landed
    __builtin_amdgcn_s_barrier();                      // all waves ready
    if (t < 15) {                                      // stage t+1: K then V
      const int nxt = cur ^ 1;
      const int kvn = (t + 1) * 64;
      const short* ks = ksrc0 + (size_t)kvn * 64;
      const short* vs = vsrc0 + kvn;
      gload16(ks,             &Ks[nxt][tid * 8]);
      gload16(ks + 32 * 64,   &Ks[nxt][(tid + 256) * 8]);
      gload16(vs,             &Vs[nxt][tid * 8]);
      gload16(vs + 32 * 1024, &Vs[nxt][(tid + 256) * 8]);
    }

    // S^T = K Q^T : lane holds q = q0+qi*16+lrow, kv = kvf*16 + lk*4 + i
    f32x4 s[2][4] = {};
    __builtin_amdgcn_s_setprio(1);
#pragma unroll
    for (int kvf = 0; kvf < 4; ++kvf) {
      const short* krow = &Ks[cur][(kvf * 16 + lrow) * 64];
      s16x8 ka0 = *(const s16x8*)&krow[ko0];
      s16x8 ka1 = *(const s16x8*)&krow[ko1];
#pragma unroll
      for (int qi = 0; qi < 2; ++qi) {
        s[qi][kvf] = __builtin_amdgcn_mfma_f32_16x16x32_bf16(ka0, qf[qi][0], s[qi][kvf], 0, 0, 0);
        s[qi][kvf] = __builtin_amdgcn_mfma_f32_16x16x32_bf16(ka1, qf[qi][1], s[qi][kvf], 0, 0, 0);
      }
    }
    __builtin_amdgcn_s_setprio(0);

    // P = exp(s - 16); lane-local row-sum slice
#pragma unroll
    for (int qi = 0; qi < 2; ++qi) {
      float acc = 0.f;
#pragma unroll
      for (int kvf = 0; kvf < 4; ++kvf)
#pragma unroll
        for (int i = 0; i < 4; ++i) {
          float p = __expf(s[qi][kvf][i] - 16.f);
          s[qi][kvf][i] = p;
          acc += p;
        }
      lr[qi] += acc;
    }

    s16x8 pf[2][2];
#pragma unroll
    for (int qi = 0; qi < 2; ++qi)
#pragma unroll
      for (int kh = 0; kh < 2; ++kh) {
        u32x4 pw;
        pw[0] = cvt_pk_bf16(s[qi][2 * kh][0],     s[qi][2 * kh][1]);
        pw[1] = cvt_pk_bf16(s[qi][2 * kh][2],     s[qi][2 * kh][3]);
        pw[2] = cvt_pk_bf16(s[qi][2 * kh + 1][0], s[qi][2 * kh + 1][1]);
        pw[3] = cvt_pk_bf16(s[qi][2 * kh + 1][2], s[qi][2 * kh + 1][3]);
        pf[qi][kh] = __builtin_bit_cast(s16x8, pw);
      }

    // V(t) landed? (leaves K/V(t+1) = 4 in flight)
    if (t < 15) asm volatile("s_waitcnt vmcnt(4)" ::: "memory");
    else        asm volatile("s_waitcnt vmcnt(0)" ::: "memory");

    __builtin_amdgcn_s_setprio(1);
#pragma unroll
    for (int ef = 0; ef < 4; ++ef) {
      const short* vrow = &Vs[cur][(ef * 16 + lrow) * 64];
#pragma unroll
      for (int kh = 0; kh < 2; ++kh) {
        s16x4 v0 = *(const s16x4*)&vrow[vo[kh][0]];
        s16x4 v1 = *(const s16x4*)&vrow[vo[kh][1]];
        s16x8 va = __builtin_shufflevector(v0, v1, 0, 1, 2, 3, 4, 5, 6, 7);
#pragma unroll
        for (int qi = 0; qi < 2; ++qi)
          o[qi][ef] = __builtin_amdgcn_mfma_f32_16x16x32_bf16(va, pf[qi][kh], o[qi][ef], 0, 0, 0);
      }
    }
    __builtin_amdgcn_s_setprio(0);
  }

#pragma unroll
  for (int qi = 0; qi < 2; ++qi) {
    lr[qi] += __shfl_xor(lr[qi], 16, 64);
    lr[qi] += __shfl_xor(lr[qi], 32, 64);
  }

  const float isq = 0.03608439182435161f;  // 1/sqrt(768)
#pragma unroll
  for (int qi = 0; qi < 2; ++qi) {
    const float inv = isq / lr[qi];
    const int q = q0 + qi * 16 + lrow;
    short* dst = Co + ((size_t)(bi * 1024 + q)) * 768 + h * 64;
#pragma unroll
    for (int ef = 0; ef < 4; ++ef) {
      u32x2 pk2;
      pk2[0] = cvt_pk_bf16(o[qi][ef][0] * inv, o[qi][ef][1] * inv);
      pk2[1] = cvt_pk_bf16(o[qi][ef][2] * inv, o[qi][ef][3] * inv);
      *(s16x4*)(dst + ef * 16 + lk * 4) = __builtin_bit_cast(s16x4, pk2);
    }
  }
}

// ------------------------------------------------------------------ launch --
extern "C" void kernel_launch(void* const* d_in, const int* in_sizes, int n_in,
                              void* d_out, int out_size, void* d_ws, size_t ws_size,
                              hipStream_t stream) {
  const float* x     = (const float*)d_in[0];
  const float* Wqk_w = (const float*)d_in[1];
  const float* Wqk_b = (const float*)d_in[2];
  const float* Wv_w  = (const float*)d_in[3];
  const float* Wv_b  = (const float*)d_in[4];
  const float* Wo_w  = (const float*)d_in[5];
  const float* Wo_b  = (const float*)d_in[6];
  float* out = (float*)d_out;

  char* w = (char*)d_ws;
  short* xb   = (short*)(w);                 // 25,165,824 B  (reused as concat)
  short* Wall = (short*)(w + 25165824);      //  4,718,592 B
  float* ball = (float*)(w + 29884416);      //     12,288 B
  short* Qb   = (short*)(w + 29896704);      // 25,165,824 B
  short* Kb   = (short*)(w + 55062528);      // 25,165,824 B
  short* VTb  = (short*)(w + 80228352);      // 25,165,824 B
  short* Co   = xb;                          // alias: x_bf16 dead after gemm<0>

  cvt_x_kernel<<<2048, 256, 0, stream>>>(x, xb, 16384 * 768 / 4);
  pack_w_kernel<<<1024, 256, 0, stream>>>(Wqk_w, Wqk_b, Wv_w, Wv_b, Wo_w, Wo_b, Wall, ball);
  gemm_bt<0><<<dim3(18, 128), 256, 0, stream>>>(xb, Wall, ball, Qb, Kb, VTb, nullptr);
  attn_kernel<<<dim3(192, 8), 256, 0, stream>>>(Qb, Kb, VTb, Co);
  gemm_bt<1><<<dim3(6, 128), 256, 0, stream>>>(Co, Wall + 2304 * 768, ball + 2304,
                                               nullptr, nullptr, nullptr, out);
}

// Round 7
// 281.302 us; speedup vs baseline: 1.2698x; 1.2698x over previous
//
#include <hip/hip_runtime.h>
#include <hip/hip_bf16.h>

// Problem: B=16, N=1024, D=768, H=12, E=64.  M = B*N = 16384.
// Pipeline: cvt_x -> pack_w -> gemm_bt<0> (QKV, writes Q,K,V^T bf16) ->
//           attn (split-wait LDS pipeline, swapped QK^T, reg softmax) ->
//           gemm_bt<1> (f32 out)

typedef __attribute__((ext_vector_type(4))) float    f32x4;
typedef __attribute__((ext_vector_type(8))) short    s16x8;
typedef __attribute__((ext_vector_type(4))) short    s16x4;
typedef __attribute__((ext_vector_type(4))) unsigned u32x4;
typedef __attribute__((ext_vector_type(2))) unsigned u32x2;

static __device__ __forceinline__ short f2bf(float f) {
  unsigned u = __builtin_bit_cast(unsigned, f);
  u += 0x7fff + ((u >> 16) & 1);          // round-to-nearest-even
  return (short)(u >> 16);
}

// v_cvt_pk_bf16_f32: D[15:0]=bf16(lo), D[31:16]=bf16(hi)
static __device__ __forceinline__ unsigned cvt_pk_bf16(float lo, float hi) {
  unsigned r;
  asm("v_cvt_pk_bf16_f32 %0, %1, %2" : "=v"(r) : "v"(lo), "v"(hi));
  return r;
}

static __device__ __forceinline__ void gload16(const void* g, void* l) {
  __builtin_amdgcn_global_load_lds(
      (const __attribute__((address_space(1))) void*)g,
      (__attribute__((address_space(3))) void*)l, 16, 0, 0);
}

// ---------------------------------------------------------------- converts --
__global__ void cvt_x_kernel(const float* __restrict__ x, short* __restrict__ xb, int n4) {
  int stride = gridDim.x * blockDim.x;
  for (int t = blockIdx.x * blockDim.x + threadIdx.x; t < n4; t += stride) {
    f32x4 v = *(const f32x4*)(x + 4 * (size_t)t);
    s16x4 o;
#pragma unroll
    for (int i = 0; i < 4; ++i) o[i] = f2bf(v[i]);
    *(s16x4*)(xb + 4 * (size_t)t) = o;
  }
}

// Pack weights bf16 into Wall[3072][768]: rows = [Q | K | V | Wo] with Q/K
// de-interleaved from Wqk's (h, e, 2) column layout.
__global__ void pack_w_kernel(const float* __restrict__ Wqk, const float* __restrict__ qkb,
                              const float* __restrict__ Wv,  const float* __restrict__ vb,
                              const float* __restrict__ Wo,  const float* __restrict__ ob,
                              short* __restrict__ Wall, float* __restrict__ ball) {
  int stride = gridDim.x * blockDim.x;
  for (int t = blockIdx.x * blockDim.x + threadIdx.x; t < 3072 * 768; t += stride) {
    int j = t / 768, k = t - j * 768;
    float v;
    if (j < 768)        v = Wqk[(((j   >> 6) << 7) + ((j    & 63) << 1) + 0) * 768 + k];
    else if (j < 1536)  { int jj = j -  768; v = Wqk[(((jj >> 6) << 7) + ((jj & 63) << 1) + 1) * 768 + k]; }
    else if (j < 2304)  { int jj = j - 1536; v = Wv[jj * 768 + k]; }
    else                { int jj = j - 2304; v = Wo[jj * 768 + k]; }
    Wall[t] = f2bf(v);
  }
  for (int t = blockIdx.x * blockDim.x + threadIdx.x; t < 3072; t += stride) {
    float v;
    if (t < 768)        v = qkb[((t >> 6) << 7) + ((t & 63) << 1)];
    else if (t < 1536)  { int jj = t -  768; v = qkb[((jj >> 6) << 7) + ((jj & 63) << 1) + 1]; }
    else if (t < 2304)  v = vb[t - 1536];
    else                v = ob[t - 2304];
    ball[t] = v;
  }
}

// ------------------------------------------------------------------- GEMM ---
// C[m][j] = sum_k A[m][k]*Bw[j][k] + bias[j].  256x128 tile, BK=32, 8 waves
// (4M x 2N; each wave = r4's proven 64x64 shape: 4+4 ds_read_b128, 16 MFMA).
// Ring-3 of 24KB bufs (A[256][32] + B[128][32]) = 72KB -> 2 blk/CU =
// 16 waves/CU.  Counted vmcnt(3) (3 stage units/tile: A-lo, A-hi, B),
// stage distance 2, one barrier/iter.  16B-granule XOR swizzle g^((r>>1)&3)
// both-sides (T2, verified r4: 18x conflict cut).  Tile efficiency
// 11.7 B/kFLOP vs 128^2's 15.2 -- attacks the measured L2->LDS delivery
// throughput bound.  Coalesced epilogue via per-wave padded LDS transpose.
// Bijective XCD swizzle (grid % 8 == 0).
template <int MODE>
__global__ __launch_bounds__(512, 4)
void gemm_bt(const short* __restrict__ A, const short* __restrict__ Bw,
             const float* __restrict__ bias,
             short* __restrict__ Qo, short* __restrict__ Ko, short* __restrict__ Vo,
             float* __restrict__ Fo) {
  __shared__ short Ls[3][12288];           // buf: A @0 (8192 sh), B @8192 (4096 sh)
  const int tid = threadIdx.x;
  const int lane = tid & 63, wid = tid >> 6;
  const int wm = wid >> 1, wn = wid & 1;   // 4M x 2N wave grid
  const int lrow = lane & 15, lk = lane >> 4;
  int lin = blockIdx.y * gridDim.x + blockIdx.x;
  const int cpx = (gridDim.x * gridDim.y) >> 3;
  lin = (lin & 7) * cpx + (lin >> 3);
  const int n0 = (lin % gridDim.x) * 128;
  const int m0 = (lin / gridDim.x) * 256;

  // staging: A = 1024 granules (thread owns tid, tid+512), B = 512 (tid).
  // phys slot j = g&3 at row r = g>>2 holds content slot j ^ ((r>>1)&3).
  const int swzc = ((tid & 3) ^ ((tid >> 3) & 3)) << 3;   // source col offset
  const short* sA = A  + (size_t)(m0 + (tid >> 2)) * 768 + swzc;
  const short* sB = Bw + (size_t)(n0 + (tid >> 2)) * 768 + swzc;
  // read side: content slot lk at phys slot lk ^ ((row>>1)&3); row%8 = lrow%8
  const int xo = (lk ^ ((lrow >> 1) & 3)) << 3;

  f32x4 acc[4][4] = {};

  // prologue: stage tiles 0,1 (3 units each; FIFO defines vmcnt retirement)
#pragma unroll
  for (int pt = 0; pt < 2; ++pt) {
    const short* gA = sA + pt * 32;
    const short* gB = sB + pt * 32;
    short* d = &Ls[pt][0];
    gload16(gA,             d + tid * 8);
    gload16(gA + 128 * 768, d + (512 + tid) * 8);
    gload16(gB,             d + 8192 + tid * 8);
  }

  int cb = 0, sb = 2;                      // kt%3, (kt+2)%3
  for (int kt = 0; kt < 24; ++kt) {
    // wait: tile kt landed (tile kt+1's 3 units stay in flight)
    if (kt < 23) asm volatile("s_waitcnt vmcnt(3)" ::: "memory");
    else         asm volatile("s_waitcnt vmcnt(0)" ::: "memory");
    __builtin_amdgcn_s_barrier();          // all waves' shares landed
    if (kt + 2 < 24) {                     // stage tile kt+2 (buf read at
      const short* gA = sA + (kt + 2) * 32;    //  kt-1; barrier kt separates)
      const short* gB = sB + (kt + 2) * 32;
      short* d = &Ls[sb][0];
      gload16(gA,             d + tid * 8);
      gload16(gA + 128 * 768, d + (512 + tid) * 8);
      gload16(gB,             d + 8192 + tid * 8);
    }
    s16x8 a[4], b[4];
#pragma unroll
    for (int mf = 0; mf < 4; ++mf)
      a[mf] = *(const s16x8*)&Ls[cb][(wm * 64 + mf * 16 + lrow) * 32 + xo];
#pragma unroll
    for (int nf = 0; nf < 4; ++nf)
      b[nf] = *(const s16x8*)&Ls[cb][8192 + (wn * 64 + nf * 16 + lrow) * 32 + xo];
    __builtin_amdgcn_s_setprio(1);
#pragma unroll
    for (int mf = 0; mf < 4; ++mf)
#pragma unroll
      for (int nf = 0; nf < 4; ++nf)
        acc[mf][nf] = __builtin_amdgcn_mfma_f32_16x16x32_bf16(a[mf], b[nf], acc[mf][nf], 0, 0, 0);
    __builtin_amdgcn_s_setprio(0);
    cb = (cb == 2) ? 0 : cb + 1;
    sb = (sb == 2) ? 0 : sb + 1;
  }

  __syncthreads();                         // repurpose Ls for epilogue
  // per-wave transpose tile [16][68] f32 = 4352 B (padded, conflict-free);
  // 8 waves x 4352 = 34.8 KB <= 72 KB.
  float* tw = (float*)((char*)&Ls[0][0] + wid * 4352);
  const int creg = n0 + wn * 64;           // this wave's 64-col range
  const int g4 = lk * 4;

  if (MODE == 0 && creg >= 1536) {
    // V^T [b,h,e,n]: direct stores (4 n's contiguous -> 8B segments)
    const int h = (creg - 1536) >> 6;
#pragma unroll
    for (int nf = 0; nf < 4; ++nf) {
      const int e = nf * 16 + lrow;
      const float bs = bias[creg + e];
#pragma unroll
      for (int mf = 0; mf < 4; ++mf) {
        f32x4 v = acc[mf][nf];
        const int mb = m0 + wm * 64 + mf * 16 + g4;
        const int bi = mb >> 10, n = mb & 1023;
        s16x4 pk;
#pragma unroll
        for (int i = 0; i < 4; ++i) pk[i] = f2bf(v[i] + bs);
        *(s16x4*)(Vo + (((size_t)bi * 12 + h) * 64 + e) * 1024 + n) = pk;
      }
    }
  } else {
#pragma unroll
    for (int mf = 0; mf < 4; ++mf) {
      // scatter fragment mf (rows g4..g4+3, col nf*16+lrow) into tw, +bias
#pragma unroll
      for (int nf = 0; nf < 4; ++nf) {
        const float bs = bias[creg + nf * 16 + lrow];
#pragma unroll
        for (int i = 0; i < 4; ++i)
          tw[(g4 + i) * 68 + nf * 16 + lrow] = acc[mf][nf][i] + bs;
      }
      // wave-internal transpose readback (ds ops ordered; no barrier needed)
      if (MODE == 0) {
        const int hq = (creg >> 6) % 12;
        short* dst0 = (creg < 768) ? Qo : Ko;
#pragma unroll
        for (int p = 0; p < 2; ++p) {
          const int row = (lane >> 3) + p * 8, c8 = (lane & 7) * 8;
          f32x4 v0 = *(const f32x4*)&tw[row * 68 + c8];
          f32x4 v1 = *(const f32x4*)&tw[row * 68 + c8 + 4];
          u32x4 pk;
          pk[0] = cvt_pk_bf16(v0[0], v0[1]);
          pk[1] = cvt_pk_bf16(v0[2], v0[3]);
          pk[2] = cvt_pk_bf16(v1[0], v1[1]);
          pk[3] = cvt_pk_bf16(v1[2], v1[3]);
          const int m = m0 + wm * 64 + mf * 16 + row;
          const int bi = m >> 10, n = m & 1023;
          *(s16x8*)(dst0 + (((size_t)bi * 12 + hq) << 16) + ((size_t)n << 6) + c8) =
              __builtin_bit_cast(s16x8, pk);
        }
      } else {
#pragma unroll
        for (int p = 0; p < 4; ++p) {
          const int row = (lane >> 4) + p * 4, c4 = (lane & 15) * 4;
          f32x4 v = *(const f32x4*)&tw[row * 68 + c4];
          const int m = m0 + wm * 64 + mf * 16 + row;
          *(f32x4*)&Fo[(size_t)m * 768 + creg + c4] = v;
        }
      }
    }
  }
}

// -------------------------------------------------------------- attention ---
// grid (192 bh, 8 qt); 4 waves x 32 q-rows share one K/V tile via LDS.
// KV tile = 64. Split-wait pipeline: top-of-iter vmcnt(2) waits only for
// K(t) (V(t) still in flight); after QK^T+softmax, vmcnt(4) waits for V(t)
// while K/V(t+1) stay in flight. One barrier per tile. LDS 16B-granule XOR
// swizzle (g ^= row&7) both sides (rule #21). Swapped QK^T keeps softmax
// lane-local; P = exp(s-16) (shift cancels in normalization); P packed
// in-register feeds PV's B-operand with k-slot permutation sigma matched by
// two 8B V reads.
__global__ __launch_bounds__(256, 4)
void attn_kernel(const short* __restrict__ Q, const short* __restrict__ K,
                 const short* __restrict__ VT, short* __restrict__ Co) {
  __shared__ short Ks[2][4096];
  __shared__ short Vs[2][4096];
  const int tid = threadIdx.x, lane = tid & 63, wid = tid >> 6;
  const int lrow = lane & 15, lk = lane >> 4;
  const int bh = blockIdx.x, qt = blockIdx.y;
  const int bi = bh / 12, h = bh - bi * 12;
  const int q0 = qt * 128 + wid * 32;
  const size_t base = (size_t)bh << 16;   // * N*E = 65536

  const short* Kb = K  + base;
  const short* Vb = VT + base;

  const int sr = tid >> 3, sj = tid & 7;
  const int jsw = (sj ^ (sr & 7)) << 3;            // element offset in row
  const short* ksrc0 = Kb + (size_t)sr * 64 + jsw;
  const short* vsrc0 = Vb + (size_t)sr * 1024 + jsw;

  const int rs = lrow & 7;
  const int ko0 = (lk ^ rs) << 3;
  const int ko1 = ((4 | lk) ^ rs) << 3;
  const int vhalf = (lk & 1) * 4;
  int vo[2][2];
#pragma unroll
  for (int kh = 0; kh < 2; ++kh) {
    const int g = kh * 4 + (lk >> 1);
    vo[kh][0] = ((g ^ rs) << 3) + vhalf;
    vo[kh][1] = (((g | 2) ^ rs) << 3) + vhalf;
  }

  s16x8 qf[2][2];
#pragma unroll
  for (int qi = 0; qi < 2; ++qi)
#pragma unroll
    for (int kk = 0; kk < 2; ++kk)
      qf[qi][kk] = *(const s16x8*)&Q[base + (size_t)(q0 + qi * 16 + lrow) * 64 + kk * 32 + lk * 8];

  f32x4 o[2][4] = {};
  float lr[2] = {0.f, 0.f};

  // prologue: K(0) then V(0)  (order defines vmcnt ledger)
  gload16(ksrc0,             &Ks[0][tid * 8]);
  gload16(ksrc0 + 32 * 64,   &Ks[0][(tid + 256) * 8]);
  gload16(vsrc0,             &Vs[0][tid * 8]);
  gload16(vsrc0 + 32 * 1024, &Vs[0][(tid + 256) * 8]);

  for (int t = 0; t < 16; ++t) {
    const int cur = t & 1;
    asm volatile("s_waitcnt vmcnt(2)" ::: "memory");   // K(t) landed
    __builtin_amdgcn_s_barrier();                      // all waves ready
    if (t < 15) {                                      // stage t+1: K then V
      const int nxt = cur ^ 1;
      const int kvn = (t + 1) * 64;
      const short* ks = ksrc0 + (size_t)kvn * 64;
      const short* vs = vsrc0 + kvn;
      gload16(ks,             &Ks[nxt][tid * 8]);
      gload16(ks + 32 * 64,   &Ks[nxt][(tid + 256) * 8]);
      gload16(vs,             &Vs[nxt][tid * 8]);
      gload16(vs + 32 * 1024, &Vs[nxt][(tid + 256) * 8]);
    }

    // S^T = K Q^T : lane holds q = q0+qi*16+lrow, kv = kvf*16 + lk*4 + i
    f32x4 s[2][4] = {};
    __builtin_amdgcn_s_setprio(1);
#pragma unroll
    for (int kvf = 0; kvf < 4; ++kvf) {
      const short* krow = &Ks[cur][(kvf * 16 + lrow) * 64];
      s16x8 ka0 = *(const s16x8*)&krow[ko0];
      s16x8 ka1 = *(const s16x8*)&krow[ko1];
#pragma unroll
      for (int qi = 0; qi < 2; ++qi) {
        s[qi][kvf] = __builtin_amdgcn_mfma_f32_16x16x32_bf16(ka0, qf[qi][0], s[qi][kvf], 0, 0, 0);
        s[qi][kvf] = __builtin_amdgcn_mfma_f32_16x16x32_bf16(ka1, qf[qi][1], s[qi][kvf], 0, 0, 0);
      }
    }
    __builtin_amdgcn_s_setprio(0);

    // P = exp(s - 16); lane-local row-sum slice
#pragma unroll
    for (int qi = 0; qi < 2; ++qi) {
      float acc = 0.f;
#pragma unroll
      for (int kvf = 0; kvf < 4; ++kvf)
#pragma unroll
        for (int i = 0; i < 4; ++i) {
          float p = __expf(s[qi][kvf][i] - 16.f);
          s[qi][kvf][i] = p;
          acc += p;
        }
      lr[qi] += acc;
    }

    s16x8 pf[2][2];
#pragma unroll
    for (int qi = 0; qi < 2; ++qi)
#pragma unroll
      for (int kh = 0; kh < 2; ++kh) {
        u32x4 pw;
        pw[0] = cvt_pk_bf16(s[qi][2 * kh][0],     s[qi][2 * kh][1]);
        pw[1] = cvt_pk_bf16(s[qi][2 * kh][2],     s[qi][2 * kh][3]);
        pw[2] = cvt_pk_bf16(s[qi][2 * kh + 1][0], s[qi][2 * kh + 1][1]);
        pw[3] = cvt_pk_bf16(s[qi][2 * kh + 1][2], s[qi][2 * kh + 1][3]);
        pf[qi][kh] = __builtin_bit_cast(s16x8, pw);
      }

    // V(t) landed? (leaves K/V(t+1) = 4 in flight)
    if (t < 15) asm volatile("s_waitcnt vmcnt(4)" ::: "memory");
    else        asm volatile("s_waitcnt vmcnt(0)" ::: "memory");

    __builtin_amdgcn_s_setprio(1);
#pragma unroll
    for (int ef = 0; ef < 4; ++ef) {
      const short* vrow = &Vs[cur][(ef * 16 + lrow) * 64];
#pragma unroll
      for (int kh = 0; kh < 2; ++kh) {
        s16x4 v0 = *(const s16x4*)&vrow[vo[kh][0]];
        s16x4 v1 = *(const s16x4*)&vrow[vo[kh][1]];
        s16x8 va = __builtin_shufflevector(v0, v1, 0, 1, 2, 3, 4, 5, 6, 7);
#pragma unroll
        for (int qi = 0; qi < 2; ++qi)
          o[qi][ef] = __builtin_amdgcn_mfma_f32_16x16x32_bf16(va, pf[qi][kh], o[qi][ef], 0, 0, 0);
      }
    }
    __builtin_amdgcn_s_setprio(0);
  }

#pragma unroll
  for (int qi = 0; qi < 2; ++qi) {
    lr[qi] += __shfl_xor(lr[qi], 16, 64);
    lr[qi] += __shfl_xor(lr[qi], 32, 64);
  }

  const float isq = 0.03608439182435161f;  // 1/sqrt(768)
#pragma unroll
  for (int qi = 0; qi < 2; ++qi) {
    const float inv = isq / lr[qi];
    const int q = q0 + qi * 16 + lrow;
    short* dst = Co + ((size_t)(bi * 1024 + q)) * 768 + h * 64;
#pragma unroll
    for (int ef = 0; ef < 4; ++ef) {
      u32x2 pk2;
      pk2[0] = cvt_pk_bf16(o[qi][ef][0] * inv, o[qi][ef][1] * inv);
      pk2[1] = cvt_pk_bf16(o[qi][ef][2] * inv, o[qi][ef][3] * inv);
      *(s16x4*)(dst + ef * 16 + lk * 4) = __builtin_bit_cast(s16x4, pk2);
    }
  }
}

// ------------------------------------------------------------------ launch --
extern "C" void kernel_launch(void* const* d_in, const int* in_sizes, int n_in,
                              void* d_out, int out_size, void* d_ws, size_t ws_size,
                              hipStream_t stream) {
  const float* x     = (const float*)d_in[0];
  const float* Wqk_w = (const float*)d_in[1];
  const float* Wqk_b = (const float*)d_in[2];
  const float* Wv_w  = (const float*)d_in[3];
  const float* Wv_b  = (const float*)d_in[4];
  const float* Wo_w  = (const float*)d_in[5];
  const float* Wo_b  = (const float*)d_in[6];
  float* out = (float*)d_out;

  char* w = (char*)d_ws;
  short* xb   = (short*)(w);                 // 25,165,824 B  (reused as concat)
  short* Wall = (short*)(w + 25165824);      //  4,718,592 B
  float* ball = (float*)(w + 29884416);      //     12,288 B
  short* Qb   = (short*)(w + 29896704);      // 25,165,824 B
  short* Kb   = (short*)(w + 55062528);      // 25,165,824 B
  short* VTb  = (short*)(w + 80228352);      // 25,165,824 B
  short* Co   = xb;                          // alias: x_bf16 dead after gemm<0>

  cvt_x_kernel<<<2048, 256, 0, stream>>>(x, xb, 16384 * 768 / 4);
  pack_w_kernel<<<1024, 256, 0, stream>>>(Wqk_w, Wqk_b, Wv_w, Wv_b, Wo_w, Wo_b, Wall, ball);
  gemm_bt<0><<<dim3(18, 64), 512, 0, stream>>>(xb, Wall, ball, Qb, Kb, VTb, nullptr);
  attn_kernel<<<dim3(192, 8), 256, 0, stream>>>(Qb, Kb, VTb, Co);
  gemm_bt<1><<<dim3(6, 64), 512, 0, stream>>>(Co, Wall + 2304 * 768, ball + 2304,
                                              nullptr, nullptr, nullptr, out);
}